// Round 4
// baseline (950.162 us; speedup 1.0000x reference)
//
#include <hip/hip_runtime.h>
#include <cfloat>

#define D 768
#define V 30523
#define NR 8192            // rows = 16*512
#define BM 128
#define BN 128
#define BK 64
#define MT (NR / BM)       // 64 row tiles
#define VT ((V + BN - 1) / BN)  // 239 col tiles

typedef __bf16 bf16x8 __attribute__((ext_vector_type(8)));
typedef float floatx4 __attribute__((ext_vector_type(4)));

__device__ __forceinline__ void async_ld16(const void* g, void* s) {
    __builtin_amdgcn_global_load_lds(
        (const __attribute__((address_space(1))) void*)g,
        (__attribute__((address_space(3))) void*)s, 16, 0, 0);
}

__device__ __forceinline__ unsigned short f2bf(float f) {
    unsigned u = __float_as_uint(f);
    unsigned r = (u + 0x7FFFu + ((u >> 16) & 1u)) >> 16;  // RNE
    return (unsigned short)r;
}

// ---------------- cast fp32 -> bf16 (vectorized) ----------------
__global__ void cast_bf16(const float* __restrict__ in, unsigned short* __restrict__ out, int n4) {
    int i = blockIdx.x * blockDim.x + threadIdx.x;
    int stride = gridDim.x * blockDim.x;
    for (; i < n4; i += stride) {
        float4 f = ((const float4*)in)[i];
        ushort4 o;
        o.x = f2bf(f.x); o.y = f2bf(f.y); o.z = f2bf(f.z); o.w = f2bf(f.w);
        ((ushort4*)out)[i] = o;
    }
}

// ---------------- label logits in fp32 (one wave per row) ----------------
__global__ void label_logit(const float* __restrict__ x, const float* __restrict__ W,
                            const float* __restrict__ bias, const int* __restrict__ lab,
                            float* __restrict__ out) {
    int wave = (blockIdx.x * blockDim.x + threadIdx.x) >> 6;
    int l = threadIdx.x & 63;
    if (wave >= NR) return;
    int lb = lab[wave];
    const float4* xr = (const float4*)(x + (size_t)wave * D);
    const float4* wr = (const float4*)(W + (size_t)lb * D);
    float s = 0.f;
#pragma unroll
    for (int k = 0; k < 3; ++k) {
        float4 a = xr[l + k * 64];
        float4 b4 = wr[l + k * 64];
        s += a.x * b4.x + a.y * b4.y + a.z * b4.z + a.w * b4.w;
    }
#pragma unroll
    for (int m = 1; m <= 32; m <<= 1) s += __shfl_xor(s, m);
    if (l == 0) out[wave] = s + bias[lb];
}

// ---------------- fused GEMM + per-tile logsumexp partials ----------------
// grid = MT*VT, block = 256 (4 waves, 2x2 wave tiles of 64x64)
__global__ __launch_bounds__(256) void gemm_lse(
    const unsigned short* __restrict__ xb, const unsigned short* __restrict__ wb,
    const float* __restrict__ bias, float* __restrict__ pm, float* __restrict__ pl) {

    __shared__ __attribute__((aligned(16))) char smem[32768];
    char* Abase = smem;            // 128x64 bf16 = 16 KB
    char* Bbase = smem + 16384;    // 128x64 bf16 = 16 KB

    const int bid = blockIdx.x;
    const int vtile = bid / MT;          // consecutive bids share W panel (L2)
    const int mtile = bid - vtile * MT;
    const int tid = threadIdx.x;
    const int w = tid >> 6;
    const int l = tid & 63;
    const int lr = l >> 3, lc = l & 7;   // staging row-in-8 / 16B granule
    const int wr = w >> 1, wc = w & 1;   // wave tile coords
    const int lg = l >> 4, li = l & 15;  // mfma fragment coords

    floatx4 acc[4][4];
#pragma unroll
    for (int a = 0; a < 4; ++a)
#pragma unroll
        for (int b = 0; b < 4; ++b) acc[a][b] = (floatx4){0.f, 0.f, 0.f, 0.f};

    for (int kt = 0; kt < D / BK; ++kt) {  // 12 iterations
        // ---- stage A,B tiles: global_load_lds, 16B per lane ----
#pragma unroll
        for (int j = 0; j < 4; ++j) {
            int row = w * 32 + j * 8 + lr;
            const unsigned short* ga = xb + (size_t)(mtile * BM + row) * D + kt * BK + lc * 8;
            async_ld16(ga, Abase + w * 4096 + j * 1024);
            int brow = vtile * BN + row;
            if (brow > V - 1) brow = V - 1;  // clamp tail (masked later)
            const unsigned short* gb = wb + (size_t)brow * D + kt * BK + lc * 8;
            async_ld16(gb, Bbase + w * 4096 + j * 1024);
        }
        __syncthreads();  // drains vmcnt -> staged data visible
        // ---- consume: 2 x K=32 chunks, 16 MFMA each ----
#pragma unroll
        for (int kk = 0; kk < 2; ++kk) {
            bf16x8 af[4], bfr[4];
#pragma unroll
            for (int mi = 0; mi < 4; ++mi)
                af[mi] = *(const bf16x8*)(Abase + (wr * 64 + mi * 16 + li) * 128 + kk * 64 + lg * 16);
#pragma unroll
            for (int ni = 0; ni < 4; ++ni)
                bfr[ni] = *(const bf16x8*)(Bbase + (wc * 64 + ni * 16 + li) * 128 + kk * 64 + lg * 16);
#pragma unroll
            for (int mi = 0; mi < 4; ++mi)
#pragma unroll
                for (int ni = 0; ni < 4; ++ni)
                    acc[mi][ni] = __builtin_amdgcn_mfma_f32_16x16x32_bf16(af[mi], bfr[ni], acc[mi][ni], 0, 0, 0);
        }
        __syncthreads();  // all reads done before next stage overwrites
    }

    // ---- epilogue: bias, mask, per-row max & sumexp over this 128-col tile ----
    float bv[4];
    int valid[4];
#pragma unroll
    for (int ni = 0; ni < 4; ++ni) {
        int col = vtile * BN + wc * 64 + ni * 16 + li;
        valid[ni] = (col < V);
        bv[ni] = valid[ni] ? bias[col] : 0.f;
    }
    float* red_m = (float*)smem;           // [2][128]
    float* red_l = (float*)(smem + 1024);  // [2][128]

#pragma unroll
    for (int mi = 0; mi < 4; ++mi) {
#pragma unroll
        for (int i = 0; i < 4; ++i) {
            float vv[4];
#pragma unroll
            for (int ni = 0; ni < 4; ++ni)
                vv[ni] = valid[ni] ? (acc[mi][ni][i] + bv[ni]) : -FLT_MAX;
            float m = fmaxf(fmaxf(vv[0], vv[1]), fmaxf(vv[2], vv[3]));
#pragma unroll
            for (int sh = 1; sh <= 8; sh <<= 1) m = fmaxf(m, __shfl_xor(m, sh));
            float s = __expf(vv[0] - m) + __expf(vv[1] - m) + __expf(vv[2] - m) + __expf(vv[3] - m);
#pragma unroll
            for (int sh = 1; sh <= 8; sh <<= 1) s += __shfl_xor(s, sh);
            if (li == 0) {
                int row = wr * 64 + mi * 16 + lg * 4 + i;
                red_m[wc * 128 + row] = m;
                red_l[wc * 128 + row] = s;
            }
        }
    }
    __syncthreads();
    if (tid < 128) {
        float m0 = red_m[tid], m1 = red_m[128 + tid];
        float l0 = red_l[tid], l1 = red_l[128 + tid];
        float m = fmaxf(m0, m1);
        float ls = l0 * __expf(m0 - m) + l1 * __expf(m1 - m);
        size_t idx = (size_t)vtile * NR + mtile * BM + tid;
        pm[idx] = m;
        pl[idx] = ls;
    }
}

// ---------------- combine partials -> mean NLL ----------------
__global__ void finalize(const float* __restrict__ pm, const float* __restrict__ pl,
                         const float* __restrict__ labl, float* __restrict__ out) {
    int r = blockIdx.x * 256 + threadIdx.x;  // 32 blocks x 256 = 8192
    float gm = -FLT_MAX, gl = 0.f;
    for (int t = 0; t < VT; ++t) {
        float m = pm[(size_t)t * NR + r];
        float s = pl[(size_t)t * NR + r];
        if (m > gm) { gl = gl * __expf(gm - m) + s; gm = m; }
        else        { gl += s * __expf(m - gm); }
    }
    float nll = logf(gl) + gm - labl[r];
#pragma unroll
    for (int m = 1; m <= 32; m <<= 1) nll += __shfl_xor(nll, m);
    __shared__ float wsum[4];
    if ((threadIdx.x & 63) == 0) wsum[threadIdx.x >> 6] = nll;
    __syncthreads();
    if (threadIdx.x == 0)
        atomicAdd(out, (wsum[0] + wsum[1] + wsum[2] + wsum[3]) * (1.0f / NR));
}

extern "C" void kernel_launch(void* const* d_in, const int* in_sizes, int n_in,
                              void* d_out, int out_size, void* d_ws, size_t ws_size,
                              hipStream_t stream) {
    const float* x = (const float*)d_in[0];
    const float* W = (const float*)d_in[1];
    const float* b = (const float*)d_in[2];
    const int* lab = (const int*)d_in[3];
    float* out = (float*)d_out;

    char* ws = (char*)d_ws;
    unsigned short* xb = (unsigned short*)ws;                      // 8192*768*2   = 12,582,912 B
    unsigned short* wb = (unsigned short*)(ws + 12582912);         // 30523*768*2  = 46,883,328 B
    float* pm = (float*)(ws + 12582912 + 46883328);                // VT*NR*4      =  7,831,552 B
    float* pl = pm + (size_t)VT * NR;                              //              =  7,831,552 B
    float* labl = pl + (size_t)VT * NR;                            // 8192*4

    hipMemsetAsync(d_out, 0, sizeof(float), stream);
    cast_bf16<<<1024, 256, 0, stream>>>(x, xb, (NR * D) / 4);
    cast_bf16<<<2048, 256, 0, stream>>>(W, wb, (V * D) / 4);
    label_logit<<<NR / 4, 256, 0, stream>>>(x, W, b, lab, labl);
    gemm_lse<<<MT * VT, 256, 0, stream>>>(xb, wb, b, pm, pl);
    finalize<<<NR / 256, 256, 0, stream>>>(pm, pl, labl, out);
}

// Round 12
// 685.498 us; speedup vs baseline: 1.3861x; 1.3861x over previous
//
#include <hip/hip_runtime.h>
#include <cfloat>

#define D 768
#define V 30523
#define NR 8192              // rows = 16*512
#define BM 128
#define BN 256
#define BK 64
#define KT (D / BK)          // 12 K-tiles
#define MT (NR / BM)         // 64 row tiles
#define VT ((V + BN - 1) / BN)  // 120 col tiles
#define AT_BYTES 16384       // 128x64 bf16
#define BT_BYTES 32768       // 256x64 bf16
#define B_OFF 49152          // 3 * AT_BYTES

typedef __bf16 bf16x8 __attribute__((ext_vector_type(8)));
typedef float floatx4 __attribute__((ext_vector_type(4)));

__device__ __forceinline__ void async_ld16(const void* g, void* s) {
    __builtin_amdgcn_global_load_lds(
        (const __attribute__((address_space(1))) void*)g,
        (__attribute__((address_space(3))) void*)s, 16, 0, 0);
}

__device__ __forceinline__ unsigned short f2bf(float f) {
    unsigned u = __float_as_uint(f);
    unsigned r = (u + 0x7FFFu + ((u >> 16) & 1u)) >> 16;  // RNE
    return (unsigned short)r;
}

// T2 catalog swizzle for 128B-row tiles read at 16B granularity:
// byte ^= (row&7)<<4  — involution (bits 7-9 untouched). Wave64 ds_read_b128:
// slot = (kk*4+lg)^(li&7) -> each 16B slot hit by exactly 8 lanes = 8 dword
// accesses/bank = the structural floor (even spread across all 32 banks).
__device__ __forceinline__ int swz(int b) { return b ^ (((b >> 7) & 7) << 4); }

// ---------------- cast fp32 -> bf16 (vectorized) ----------------
__global__ void cast_bf16(const float* __restrict__ in, unsigned short* __restrict__ out, int n4) {
    int i = blockIdx.x * blockDim.x + threadIdx.x;
    int stride = gridDim.x * blockDim.x;
    for (; i < n4; i += stride) {
        float4 f = ((const float4*)in)[i];
        ushort4 o;
        o.x = f2bf(f.x); o.y = f2bf(f.y); o.z = f2bf(f.z); o.w = f2bf(f.w);
        ((ushort4*)out)[i] = o;
    }
}

// ---------------- label logits in fp32 (one wave per row) ----------------
__global__ void label_logit(const float* __restrict__ x, const float* __restrict__ W,
                            const float* __restrict__ bias, const int* __restrict__ lab,
                            float* __restrict__ out) {
    int wave = (blockIdx.x * blockDim.x + threadIdx.x) >> 6;
    int l = threadIdx.x & 63;
    if (wave >= NR) return;
    int lb = lab[wave];
    const float4* xr = (const float4*)(x + (size_t)wave * D);
    const float4* wr = (const float4*)(W + (size_t)lb * D);
    float s = 0.f;
#pragma unroll
    for (int k = 0; k < 3; ++k) {
        float4 a = xr[l + k * 64];
        float4 b4 = wr[l + k * 64];
        s += a.x * b4.x + a.y * b4.y + a.z * b4.z + a.w * b4.w;
    }
#pragma unroll
    for (int m = 1; m <= 32; m <<= 1) s += __shfl_xor(s, m);
    if (l == 0) out[wave] = s + bias[lb];
}

// ---------------- fused GEMM + per-tile logsumexp partials ----------------
// 128x256 tile, 8 waves (2M x 4N, wave tile 64x64), BK=64, triple-buffered LDS,
// counted vmcnt(6), one raw s_barrier per K-tile, T2 swizzle, T5 setprio.
__global__ __launch_bounds__(512, 1) void gemm_lse(
    const unsigned short* __restrict__ xb, const unsigned short* __restrict__ wb,
    const float* __restrict__ bias, float* __restrict__ pm, float* __restrict__ pl) {

    __shared__ __attribute__((aligned(16))) char smem[147456];  // 3*16K A + 3*32K B

    const int bid = blockIdx.x;
    const int vtile = bid / MT;          // consecutive bids share the W panel (L2)
    const int mtile = bid - vtile * MT;
    const int tid = threadIdx.x;         // 0..511
    const int l = tid & 63;
    const int w = tid >> 6;
    const int wr = w >> 2, wc = w & 3;   // 2M x 4N wave grid
    const int lg = l >> 4, li = l & 15;  // mfma fragment coords

    // ---- staging: LDS dest linear (tid*16), global source inverse-swizzled ----
    const unsigned short* gA[2];
    int ldsA[2];
#pragma unroll
    for (int j = 0; j < 2; ++j) {
        int Lb = j * 8192 + tid * 16;
        int row = Lb >> 7;
        int colB = (Lb & 127) ^ ((row & 7) << 4);
        gA[j] = xb + (size_t)(mtile * BM + row) * D + (colB >> 1);
        ldsA[j] = Lb;
    }
    const unsigned short* gB[4];
    int ldsB[4];
#pragma unroll
    for (int j = 0; j < 4; ++j) {
        int Lb = j * 8192 + tid * 16;
        int row = Lb >> 7;
        int colB = (Lb & 127) ^ ((row & 7) << 4);
        int brow = vtile * BN + row;
        if (brow > V - 1) brow = V - 1;  // clamp tail rows (masked in epilogue)
        gB[j] = wb + (size_t)brow * D + (colB >> 1);
        ldsB[j] = Lb;
    }

    // ---- swizzled ds_read offsets ----
    int aoff[2][4], boff[2][4];
#pragma unroll
    for (int kk = 0; kk < 2; ++kk) {
#pragma unroll
        for (int mi = 0; mi < 4; ++mi)
            aoff[kk][mi] = swz((wr * 64 + mi * 16 + li) * 128 + kk * 64 + lg * 16);
#pragma unroll
        for (int ni = 0; ni < 4; ++ni)
            boff[kk][ni] = swz((wc * 64 + ni * 16 + li) * 128 + kk * 64 + lg * 16);
    }

    floatx4 acc[4][4];
#pragma unroll
    for (int a = 0; a < 4; ++a)
#pragma unroll
        for (int b = 0; b < 4; ++b) acc[a][b] = (floatx4){0.f, 0.f, 0.f, 0.f};

    // ---- prologue: stage tiles 0 and 1 (6 loads per tile per thread) ----
#pragma unroll
    for (int j = 0; j < 2; ++j) async_ld16(gA[j], smem + 0 * AT_BYTES + ldsA[j]);
#pragma unroll
    for (int j = 0; j < 4; ++j) async_ld16(gB[j], smem + B_OFF + 0 * BT_BYTES + ldsB[j]);
#pragma unroll
    for (int j = 0; j < 2; ++j) async_ld16(gA[j] + BK, smem + 1 * AT_BYTES + ldsA[j]);
#pragma unroll
    for (int j = 0; j < 4; ++j) async_ld16(gB[j] + BK, smem + B_OFF + 1 * BT_BYTES + ldsB[j]);

    // ---- main loop: one K-tile per iteration, single barrier, counted vmcnt ----
    for (int t = 0; t < KT; ++t) {
        if (t == KT - 1) { asm volatile("s_waitcnt vmcnt(0)" ::: "memory"); }
        else             { asm volatile("s_waitcnt vmcnt(6)" ::: "memory"); }
        __builtin_amdgcn_s_barrier();
        __builtin_amdgcn_sched_barrier(0);

        const int cur = t % 3;
        // stage tile t+2 into buffer (t+2)%3 == (t-1)%3 (its reads done: barrier above)
        if (t + 2 < KT) {
            const int nb = (t + 2) % 3;
            const int koff = (t + 2) * BK;
#pragma unroll
            for (int j = 0; j < 2; ++j) async_ld16(gA[j] + koff, smem + nb * AT_BYTES + ldsA[j]);
#pragma unroll
            for (int j = 0; j < 4; ++j) async_ld16(gB[j] + koff, smem + B_OFF + nb * BT_BYTES + ldsB[j]);
        }

        const char* Ab = smem + cur * AT_BYTES;
        const char* Bb = smem + B_OFF + cur * BT_BYTES;
        bf16x8 af[2][4], bf[2][4];
#pragma unroll
        for (int kk = 0; kk < 2; ++kk) {
#pragma unroll
            for (int mi = 0; mi < 4; ++mi) af[kk][mi] = *(const bf16x8*)(Ab + aoff[kk][mi]);
#pragma unroll
            for (int ni = 0; ni < 4; ++ni) bf[kk][ni] = *(const bf16x8*)(Bb + boff[kk][ni]);
        }
        __builtin_amdgcn_s_setprio(1);
#pragma unroll
        for (int kk = 0; kk < 2; ++kk)
#pragma unroll
            for (int mi = 0; mi < 4; ++mi)
#pragma unroll
                for (int ni = 0; ni < 4; ++ni)
                    acc[mi][ni] = __builtin_amdgcn_mfma_f32_16x16x32_bf16(af[kk][mi], bf[kk][ni], acc[mi][ni], 0, 0, 0);
        __builtin_amdgcn_s_setprio(0);
    }

    // ---- epilogue: bias, mask, per-row max & sumexp over this 256-col tile ----
    float bv[4];
    int valid[4];
#pragma unroll
    for (int ni = 0; ni < 4; ++ni) {
        int col = vtile * BN + wc * 64 + ni * 16 + li;
        valid[ni] = (col < V);
        bv[ni] = valid[ni] ? bias[col] : 0.f;
    }
    float* red_m = (float*)smem;           // [4][128]
    float* red_l = (float*)(smem + 2048);  // [4][128]
    __syncthreads();  // all waves done with K-loop LDS before reuse

#pragma unroll
    for (int mi = 0; mi < 4; ++mi) {
#pragma unroll
        for (int i = 0; i < 4; ++i) {
            float vv[4];
#pragma unroll
            for (int ni = 0; ni < 4; ++ni)
                vv[ni] = valid[ni] ? (acc[mi][ni][i] + bv[ni]) : -FLT_MAX;
            float m = fmaxf(fmaxf(vv[0], vv[1]), fmaxf(vv[2], vv[3]));
#pragma unroll
            for (int sh = 1; sh <= 8; sh <<= 1) m = fmaxf(m, __shfl_xor(m, sh));
            float s = __expf(vv[0] - m) + __expf(vv[1] - m) + __expf(vv[2] - m) + __expf(vv[3] - m);
#pragma unroll
            for (int sh = 1; sh <= 8; sh <<= 1) s += __shfl_xor(s, sh);
            if (li == 0) {
                int row = wr * 64 + mi * 16 + lg * 4 + i;  // 0..127
                red_m[wc * 128 + row] = m;
                red_l[wc * 128 + row] = s;
            }
        }
    }
    __syncthreads();
    if (tid < 128) {
        float m0 = red_m[tid],       l0 = red_l[tid];
        float m1 = red_m[128 + tid], l1 = red_l[128 + tid];
        float m2 = red_m[256 + tid], l2 = red_l[256 + tid];
        float m3 = red_m[384 + tid], l3 = red_l[384 + tid];
        float m = fmaxf(fmaxf(m0, m1), fmaxf(m2, m3));
        float ls = l0 * __expf(m0 - m) + l1 * __expf(m1 - m) +
                   l2 * __expf(m2 - m) + l3 * __expf(m3 - m);
        size_t idx = (size_t)vtile * NR + mtile * BM + tid;
        pm[idx] = m;
        pl[idx] = ls;
    }
}

// ---------------- combine partials -> mean NLL ----------------
__global__ void finalize(const float* __restrict__ pm, const float* __restrict__ pl,
                         const float* __restrict__ labl, float* __restrict__ out) {
    int r = blockIdx.x * 256 + threadIdx.x;  // 32 blocks x 256 = 8192
    float gm = -FLT_MAX, gl = 0.f;
    for (int t = 0; t < VT; ++t) {
        float m = pm[(size_t)t * NR + r];
        float s = pl[(size_t)t * NR + r];
        if (m > gm) { gl = gl * __expf(gm - m) + s; gm = m; }
        else        { gl += s * __expf(m - gm); }
    }
    float nll = logf(gl) + gm - labl[r];
#pragma unroll
    for (int m = 1; m <= 32; m <<= 1) nll += __shfl_xor(nll, m);
    __shared__ float wsum[4];
    if ((threadIdx.x & 63) == 0) wsum[threadIdx.x >> 6] = nll;
    __syncthreads();
    if (threadIdx.x == 0)
        atomicAdd(out, (wsum[0] + wsum[1] + wsum[2] + wsum[3]) * (1.0f / NR));
}

extern "C" void kernel_launch(void* const* d_in, const int* in_sizes, int n_in,
                              void* d_out, int out_size, void* d_ws, size_t ws_size,
                              hipStream_t stream) {
    const float* x = (const float*)d_in[0];
    const float* W = (const float*)d_in[1];
    const float* b = (const float*)d_in[2];
    const int* lab = (const int*)d_in[3];
    float* out = (float*)d_out;

    char* ws = (char*)d_ws;
    unsigned short* xb = (unsigned short*)ws;                      // 8192*768*2   = 12,582,912 B
    unsigned short* wb = (unsigned short*)(ws + 12582912);         // 30523*768*2  = 46,883,328 B
    float* pm = (float*)(ws + 12582912 + 46883328);                // VT*NR*4      =  3,932,160 B
    float* pl = pm + (size_t)VT * NR;                              //              =  3,932,160 B
    float* labl = pl + (size_t)VT * NR;                            // 8192*4

    hipMemsetAsync(d_out, 0, sizeof(float), stream);
    cast_bf16<<<1024, 256, 0, stream>>>(x, xb, (NR * D) / 4);
    cast_bf16<<<2048, 256, 0, stream>>>(W, wb, (V * D) / 4);
    label_logit<<<NR / 4, 256, 0, stream>>>(x, W, b, lab, labl);
    gemm_lse<<<MT * VT, 512, 0, stream>>>(xb, wb, b, pm, pl);
    finalize<<<NR / 256, 256, 0, stream>>>(pm, pl, labl, out);
}